// Round 8
// baseline (305.939 us; speedup 1.0000x reference)
//
#include <hip/hip_runtime.h>

typedef unsigned long long ull;

#define NANCH   131072
#define NMAX    64
#define NBATCH  16
#define THREADS 256
#define CHA     1024                 // anchors per block
#define NCHUNK  (NANCH/CHA)          // 128
#define MAXB    16                   // max bundles
#define GRID    (MAXB*NCHUNK)        // 2048 blocks (inactive bundles exit)

// ---------------------------------------------------------------------------
// ws layout (bytes):
//   0      : ull cells[1024]        per-(batch,gt) packed argmax
//   8192   : int lanepk[16*64]      bundle lane -> (batch<<8)|gt, -1 invalid
//   12288  : int nbund
//   12352  : int nspan[16]
//   12416  : int spanb[16*4]        span batch ids
//   12672  : ull spanm[16*4]        span lane masks
//   16384  : double partials[2048]
// cells packed as (iou_bits<<32)|(0x7FFFFFFF-idx): iou>=0 so float bits are
// unsigned-monotonic; ties -> larger low word -> smaller anchor index == JAX
// argmax first-occurrence semantics.
// ---------------------------------------------------------------------------

__global__ __launch_bounds__(64) void k_setup(
    const int* __restrict__ nobj,
    ull* __restrict__ cells, int* __restrict__ nbund, int* __restrict__ lanepk,
    int* __restrict__ nspan, int* __restrict__ spanb, ull* __restrict__ spanm)
{
    int tid = threadIdx.x;
    for (int i = tid; i < NBATCH*NMAX; i += 64) cells[i] = 0ull;
    if (tid) return;
    // sort batches desc by n_obj (stable)
    int ord[NBATCH], key[NBATCH];
    for (int i = 0; i < NBATCH; ++i) { ord[i] = i; key[i] = nobj[i]; }
    for (int i = 1; i < NBATCH; ++i) {
        int k = key[i], o = ord[i], j = i-1;
        while (j >= 0 && key[j] < k) { key[j+1]=key[j]; ord[j+1]=ord[j]; --j; }
        key[j+1] = k; ord[j+1] = o;
    }
    // first-fit-decreasing into 64-lane bundles, <=4 spans each
    int rem[MAXB], nsp_[MAXB];
    int sb_[MAXB][4], st_[MAXB][4], sl_[MAXB][4];
    int nb = 0;
    for (int i = 0; i < NBATCH; ++i) {
        int n = key[i], f = -1;
        for (int x = 0; x < nb; ++x) if (rem[x] >= n && nsp_[x] < 4) { f = x; break; }
        if (f < 0) { f = nb++; rem[f] = NMAX; nsp_[f] = 0; }
        int s = nsp_[f]++;
        sb_[f][s] = ord[i]; st_[f][s] = NMAX - rem[f]; sl_[f][s] = n;
        rem[f] -= n;
    }
    *nbund = nb;
    for (int bu = 0; bu < MAXB; ++bu) {
        int ns = (bu < nb) ? nsp_[bu] : 0;
        nspan[bu] = ns;
        for (int l = 0; l < NMAX; ++l) lanepk[bu*NMAX + l] = -1;
        for (int s = 0; s < 4; ++s) { spanb[bu*4+s] = 0; spanm[bu*4+s] = 0ull; }
        for (int s = 0; s < ns; ++s) {
            int b = sb_[bu][s], st = st_[bu][s], ln = sl_[bu][s];
            spanb[bu*4+s] = b;
            spanm[bu*4+s] = (ln >= 64) ? ~0ull : ((((ull)1 << ln) - 1) << st);
            for (int k = 0; k < ln; ++k) lanepk[bu*NMAX + st + k] = (b << 8) | k;
        }
    }
}

// gt-per-lane main pass: wave iterates anchors broadcast from LDS. Per-gt
// argmax is LANE-LOCAL (no cross-lane reduction); per-anchor count is ONE
// ballot -> scalar-pipe popcount -> (ln==j) select into a per-lane slot for
// a vectorized focal epilogue every 64 anchors.
__global__ __launch_bounds__(THREADS) void k_main(
    const float* __restrict__ thr_p,
    const float* __restrict__ classes,   // [B,A,2]
    const float* __restrict__ anchors,   // [A,4] xyxy
    const float* __restrict__ gt,        // [B,NMAX,4] xywh
    ull* __restrict__ cells,
    const int* __restrict__ nbund, const int* __restrict__ lanepk,
    const int* __restrict__ nspan, const int* __restrict__ spanb,
    const ull* __restrict__ spanm,
    double* __restrict__ partials)
{
    int bu  = blockIdx.x & (MAXB-1);
    int ch  = blockIdx.x >> 4;
    int tid = threadIdx.x;
    int nb  = *nbund;
    if (bu >= nb) { if (tid == 0) partials[blockIdx.x] = 0.0; return; }

    float thr = *thr_p;
    float q   = thr / (1.0f + thr);      // iou>thr <=> inter > q*aar + q*gar

    __shared__ float4 sA[CHA];           // anchor boxes (xyxy)       16KB
    __shared__ float2 sPQ[CHA];          // (area, q*area)             8KB
    __shared__ double sw[4];

    const float4* ap = reinterpret_cast<const float4*>(anchors) + ch*CHA;
    for (int i = tid; i < CHA; i += THREADS) {
        float4 v = ap[i];
        float ar = (v.z - v.x) * (v.w - v.y);
        sA[i]  = v;
        sPQ[i] = make_float2(ar, q * ar);
    }

    int wv = tid >> 6, ln = tid & 63;

    // this lane's gt
    int lp = lanepk[bu*NMAX + ln];
    bool valid = lp >= 0;
    float gx1 = 0.f, gy1 = 0.f, gx2 = 0.f, gy2 = 0.f, gar = 0.f;
    float qg  = __builtin_inff();        // invalid lanes: pred always false
    if (valid) {
        float4 gg = reinterpret_cast<const float4*>(gt)[(lp >> 8)*NMAX + (lp & 255)];
        float x2 = gg.x + gg.z, y2 = gg.y + gg.w;
        gx1 = gg.x; gy1 = gg.y; gx2 = x2; gy2 = y2;
        gar = (x2 - gg.x) * (y2 - gg.y);
        qg  = q * gar;
    }

    // wave-uniform span info
    int nsp = __builtin_amdgcn_readfirstlane(nspan[bu]);
    int sb0 = __builtin_amdgcn_readfirstlane(spanb[bu*4+0]);
    int sb1 = __builtin_amdgcn_readfirstlane(spanb[bu*4+1]);
    int sb2 = __builtin_amdgcn_readfirstlane(spanb[bu*4+2]);
    int sb3 = __builtin_amdgcn_readfirstlane(spanb[bu*4+3]);
    const unsigned* sm32 = reinterpret_cast<const unsigned*>(spanm + bu*4);
    #define RDU64(IX) ((((ull)(unsigned)__builtin_amdgcn_readfirstlane((int)sm32[2*(IX)+1])) << 32) \
                      | (ull)(unsigned)__builtin_amdgcn_readfirstlane((int)sm32[2*(IX)]))
    ull sm0 = RDU64(0), sm1 = RDU64(1), sm2 = RDU64(2), sm3 = RDU64(3);
    #undef RDU64

    __syncthreads();

    double acc = 0.0;
    float bn = -1.0f, bd = 1.0f;         // running best (inter, den) for lane's gt
    int bxj = 0, bxg = 0;                // best anchor = gi*64 + j
    const float2* cls2 = reinterpret_cast<const float2*>(classes);
    int wbase = wv * 256;

    for (int gi = 0; gi < 4; ++gi) {
        int gb = wbase + gi*64;
        int cnt0v = 0, cnt1v = 0, cnt2v = 0, cnt3v = 0;
        #pragma unroll
        for (int j = 0; j < 64; ++j) {
            float4 B  = sA[gb + j];      // broadcast (uniform addr, conflict-free)
            float2 PQ = sPQ[gb + j];
            float lx = fmaxf(B.x, gx1);
            float ly = fmaxf(B.y, gy1);
            float rx = fminf(B.z, gx2);
            float ry = fminf(B.w, gy2);
            float w  = fmaxf(rx - lx, 0.f);
            float h  = fmaxf(ry - ly, 0.f);
            float inter = w * h;
            float den   = (PQ.x + gar) - inter;      // > 0 for real pairs
            // lane-local argmax: iouA > iouBest <=> interA*bd > bn*denA
            bool better = inter * bd > bn * den;
            bn  = better ? inter : bn;
            bd  = better ? den   : bd;
            bxj = better ? j     : bxj;
            bxg = better ? gi    : bxg;
            // count: iou > thr  <=>  inter > q*aar + q*gar
            bool pred = inter > PQ.y + qg;
            ull m = __ballot(pred);      // wave-uniform (SGPR pair)
            // scalar-pipe popcounts; lane j keeps anchor j's count
            bool mine = (ln == j);
            int c0 = (int)__popcll(m & sm0);
            cnt0v = mine ? c0 : cnt0v;
            if (nsp > 1) { int c1 = (int)__popcll(m & sm1); cnt1v = mine ? c1 : cnt1v; }
            if (nsp > 2) { int c2 = (int)__popcll(m & sm2); cnt2v = mine ? c2 : cnt2v; }
            if (nsp > 3) { int c3 = (int)__popcll(m & sm3); cnt3v = mine ? c3 : cnt3v; }
        }
        // focal epilogue: lane l <-> anchor gb+l of this group
        int abase = ch*CHA + gb + ln;
        #define SPAN_EPI(SB, CV) { \
            float2 c = cls2[(size_t)(SB)*NANCH + abase]; \
            int cnt  = (CV); \
            float p  = cnt > 0 ? c.y : c.x; \
            float om = 1.0f - p; \
            float f  = -om * om * __logf(p); \
            acc += (double)(f * (1.0f + 10.0f * (float)cnt)); }
        SPAN_EPI(sb0, cnt0v)
        if (nsp > 1) SPAN_EPI(sb1, cnt1v)
        if (nsp > 2) SPAN_EPI(sb2, cnt2v)
        if (nsp > 3) SPAN_EPI(sb3, cnt3v)
        #undef SPAN_EPI
    }

    if (valid) {                          // one 64-lane atomic per wave
        float iou = bn * __builtin_amdgcn_rcpf(bd);   // order only
        unsigned aidx = (unsigned)(ch*CHA + wbase + bxg*64 + bxj);
        ull pk = ((ull)__float_as_uint(iou) << 32) | (ull)(0x7FFFFFFFu - aidx);
        atomicMax(&cells[(lp >> 8)*NMAX + (lp & 255)], pk);
    }

    #pragma unroll
    for (int off = 32; off; off >>= 1) acc += __shfl_xor(acc, off, 64);
    if (ln == 0) sw[wv] = acc;
    __syncthreads();
    if (tid == 0) partials[blockIdx.x] = sw[0] + sw[1] + sw[2] + sw[3];
}

// One block, 1024 threads: sparse forced-positive correction (batch = tid>>6)
// + final reduction. Predicate expressions textually identical to k_main so
// the "old" contribution cancels exactly.
__global__ __launch_bounds__(1024) void k_tail(
    const float* __restrict__ thr_p,
    const float* __restrict__ classes,
    const float* __restrict__ anchors,
    const float* __restrict__ gt,
    const int*   __restrict__ nobj,
    const ull*   __restrict__ cells,
    const double* __restrict__ partials,
    float* __restrict__ out)
{
    int tid = threadIdx.x;
    int b = tid >> 6, n = tid & 63;
    float thr = *thr_p;
    float q   = thr / (1.0f + thr);

    __shared__ float4 sbox[NBATCH*NMAX];
    __shared__ float  sqg[NBATCH*NMAX];
    __shared__ int    sidx[NBATCH*NMAX];
    __shared__ double sdelta[NBATCH];
    __shared__ double sw[16];

    int n_obj = nobj[b];
    {
        float4 g = reinterpret_cast<const float4*>(gt)[b*NMAX + n];
        float x2 = g.x + g.z, y2 = g.y + g.w;
        sbox[tid] = make_float4(g.x, g.y, x2, y2);
        float gar = (x2 - g.x) * (y2 - g.y);
        sqg[tid]  = q * gar;
    }
    __syncthreads();

    int bi = -1; bool need = false;
    float4 av = make_float4(0.f,0.f,0.f,0.f);
    float qa = 0.f;
    if (n < n_obj) {
        ull pkv = cells[tid];
        bi = (int)(0x7FFFFFFFu - (unsigned)(pkv & 0xFFFFFFFFull));
        av = reinterpret_cast<const float4*>(anchors)[bi];
        float aar = (av.z - av.x) * (av.w - av.y);
        qa = q * aar;
        float4 g = sbox[tid];
        float lx = fmaxf(av.x, g.x), ly = fmaxf(av.y, g.y);
        float rx = fminf(av.z, g.z), ry = fminf(av.w, g.w);
        float w  = fmaxf(rx - lx, 0.f), h = fmaxf(ry - ly, 0.f);
        float inter = w * h;
        need = !(inter > qa + sqg[tid]);  // forced adds a bit only if !pos
    }
    sidx[tid] = need ? bi : -1;
    __syncthreads();

    double delta = 0.0;
    if (need) {
        bool first = true; int extra = 0;
        int base = b * NMAX;
        for (int m = 0; m < NMAX; ++m) {
            if (sidx[base + m] == bi) { if (m < n) first = false; ++extra; }
        }
        if (first) {
            int count = 0;
            for (int m = 0; m < n_obj; ++m) {
                float4 g = sbox[base + m];
                float lx = fmaxf(av.x, g.x), ly = fmaxf(av.y, g.y);
                float rx = fminf(av.z, g.z), ry = fminf(av.w, g.w);
                float w  = fmaxf(rx - lx, 0.f), h = fmaxf(ry - ly, 0.f);
                float inter = w * h;
                count += (inter > qa + sqg[base + m]) ? 1 : 0;
            }
            float2 c = reinterpret_cast<const float2*>(classes)[(size_t)b * NANCH + bi];
            float po = (count > 0) ? c.y : c.x;
            float oo = 1.0f - po;
            float fo = -oo * oo * __logf(po);
            float oldc = fo * (1.0f + 10.0f * (float)count);
            int cn = count + extra;
            float pn = (cn > 0) ? c.y : c.x;
            float on = 1.0f - pn;
            float fn = -on * on * __logf(pn);
            float newc = fn * (1.0f + 10.0f * (float)cn);
            delta = (double)newc - (double)oldc;
        }
    }
    #pragma unroll
    for (int off = 32; off; off >>= 1) delta += __shfl_xor(delta, off, 64);
    if (n == 0) sdelta[b] = delta;
    __syncthreads();

    // final: 2048 partials (2 per thread) + 16 deltas
    double v = partials[tid] + partials[tid + 1024];
    if (tid < NBATCH) v += sdelta[tid];
    #pragma unroll
    for (int off = 32; off; off >>= 1) v += __shfl_xor(v, off, 64);
    if ((tid & 63) == 0) sw[tid >> 6] = v;
    __syncthreads();
    if (tid == 0) {
        double tot = 0.0;
        #pragma unroll
        for (int i = 0; i < 16; ++i) tot += sw[i];
        double cls = tot * (0.01 / 16.0);
        out[0] = (float)cls;   // total = class + coord(0)
        out[1] = (float)cls;
        out[2] = 0.0f;
    }
}

extern "C" void kernel_launch(void* const* d_in, const int* in_sizes, int n_in,
                              void* d_out, int out_size, void* d_ws, size_t ws_size,
                              hipStream_t stream) {
    const float* thr     = (const float*)d_in[0];
    const float* classes = (const float*)d_in[1];
    const float* anchors = (const float*)d_in[2];
    const float* gt      = (const float*)d_in[3];
    const int*   nobj    = (const int*)d_in[4];
    float* out = (float*)d_out;

    char* ws = (char*)d_ws;
    ull*    cells    = (ull*)(ws + 0);
    int*    lanepk   = (int*)(ws + 8192);
    int*    nbund    = (int*)(ws + 12288);
    int*    nspan    = (int*)(ws + 12352);
    int*    spanb    = (int*)(ws + 12416);
    ull*    spanm    = (ull*)(ws + 12672);
    double* partials = (double*)(ws + 16384);

    k_setup<<<1, 64, 0, stream>>>(nobj, cells, nbund, lanepk, nspan, spanb, spanm);
    k_main<<<GRID, THREADS, 0, stream>>>(thr, classes, anchors, gt, cells,
                                         nbund, lanepk, nspan, spanb, spanm, partials);
    k_tail<<<1, 1024, 0, stream>>>(thr, classes, anchors, gt, nobj, cells, partials, out);
}

// Round 9
// 106.940 us; speedup vs baseline: 2.8608x; 2.8608x over previous
//
#include <hip/hip_runtime.h>

typedef unsigned long long ull;

#define NANCH    131072
#define NMAX     64
#define NBATCH   16
#define THREADS  256
#define APT      4                       // count role: anchors per thread
#define ACH      (THREADS*APT)           // 1024 anchors per count block
#define NPAIR    8
#define NB_CNT   ((NANCH/ACH)*NPAIR)     // 1024 count blocks
#define AC_ANCH  256                     // argmax role: anchors per wave-chunk
#define NCHUNK_A (NANCH/AC_ANCH)         // 512 chunks
#define BPB_A    (NCHUNK_A/4)            // 128 blocks per bundle (4 waves each)
#define MAXB     16
#define NB_ARG   (MAXB*BPB_A)            // 2048 argmax blocks
#define GRID_MAIN (NB_CNT+NB_ARG)

// ---------------------------------------------------------------------------
// ws layout (bytes):
//   0      : ull cells[1024]       per-(batch,gt) packed argmax
//   8192   : int pairs[16]         batch pairing for count-role balance
//   8256   : int lanepk[16*64]     bundle lane -> (batch<<8)|gt, -1 invalid
//   12352  : int nbund
//   12416  : double partials[1024] count-block sums
// cells packed as (r_bits<<32)|(0x7FFFFFFF-idx), r = inter/(areaA+areaB) --
// a monotone bijection of iou, >= 0, so float bits are unsigned-monotonic;
// ties -> larger low word -> smaller anchor index == JAX argmax
// first-occurrence semantics.
// ---------------------------------------------------------------------------

__global__ __launch_bounds__(64) void k_setup(
    const int* __restrict__ nobj, ull* __restrict__ cells,
    int* __restrict__ pairs, int* __restrict__ lanepk, int* __restrict__ nbund)
{
    int tid = threadIdx.x;
    for (int i = tid; i < NBATCH*NMAX; i += 64) cells[i] = 0ull;
    for (int i = tid; i < MAXB*NMAX; i += 64) lanepk[i] = -1;
    __syncthreads();
    if (tid) return;
    // sort batches desc by n_obj (stable)
    int ord[NBATCH], key[NBATCH];
    for (int i = 0; i < NBATCH; ++i) { ord[i] = i; key[i] = nobj[i]; }
    for (int i = 1; i < NBATCH; ++i) {
        int k = key[i], o = ord[i], j = i-1;
        while (j >= 0 && key[j] < k) { key[j+1]=key[j]; ord[j+1]=ord[j]; --j; }
        key[j+1] = k; ord[j+1] = o;
    }
    // count-role pairing: big + small -> near-equal sums
    for (int p = 0; p < NPAIR; ++p) {
        pairs[2*p]   = ord[p];
        pairs[2*p+1] = ord[NBATCH-1-p];
    }
    // argmax-role: first-fit-decreasing into 64-lane bundles
    int rem[MAXB];
    int nb = 0;
    for (int i = 0; i < NBATCH; ++i) {
        int n = key[i], f = -1;
        for (int x = 0; x < nb; ++x) if (rem[x] >= n) { f = x; break; }
        if (f < 0) { f = nb++; rem[f] = NMAX; }
        int st = NMAX - rem[f];
        for (int k = 0; k < n; ++k) lanepk[f*NMAX + st + k] = (ord[i] << 8) | k;
        rem[f] -= n;
    }
    *nbund = nb;
}

// Two roles in one launch so they overlap on the machine:
//  - count role: anchor-per-lane, gts from LDS, 12-op inner, NO reductions.
//  - argmax role: (batch,gt)-per-lane via bundles, 4 independent unroll-slot
//    chains per lane, NO cross-lane ops, one atomicMax per lane at the end.
__global__ __launch_bounds__(THREADS, 6) void k_main(
    const float* __restrict__ thr_p,
    const float* __restrict__ classes,   // [B,A,2]
    const float* __restrict__ anchors,   // [A,4] xyxy
    const float* __restrict__ gt,        // [B,NMAX,4] xywh
    const int*   __restrict__ nobj,
    const int*   __restrict__ pairs,
    const int*   __restrict__ lanepk,
    const int*   __restrict__ nbund,
    ull* __restrict__ cells,
    double* __restrict__ partials)
{
    int bid = blockIdx.x;
    int tid = threadIdx.x;
    float thr = *thr_p;
    float q   = thr / (1.0f + thr);      // iou>thr <=> inter > q*aarea + q*garea

    if (bid < NB_CNT) {
        // ==================== count + focal role ====================
        int chunk = bid >> 3, pr = bid & 7;
        int b0 = pairs[2*pr], b1 = pairs[2*pr+1];
        int no0 = nobj[b0], no1 = nobj[b1];

        __shared__ float4 sbox[2*NMAX];  // xyxy (degenerate-padded)
        __shared__ float  sqg[2*NMAX];   // q*garea (+inf for pads)
        __shared__ double sw[4];
        if (tid < 2*NMAX) {
            int s = tid >> 6, n = tid & 63;
            int b  = s ? b1 : b0;
            int no = s ? no1 : no0;
            float4 g = reinterpret_cast<const float4*>(gt)[b*NMAX + n];
            float x2 = g.x + g.z, y2 = g.y + g.w;
            float4 box = make_float4(g.x, g.y, x2, y2);
            float  qg  = q * ((x2 - g.x) * (y2 - g.y));
            if (n >= no) { box = make_float4(4.f,4.f,4.f,4.f); qg = __builtin_inff(); }
            sbox[tid] = box; sqg[tid] = qg;
        }
        __syncthreads();

        float ax1[APT], ay1[APT], ax2[APT], ay2[APT], qa[APT];
        int abase = chunk * ACH + tid;
        #pragma unroll
        for (int k = 0; k < APT; ++k) {
            float4 v = reinterpret_cast<const float4*>(anchors)[abase + k*THREADS];
            ax1[k]=v.x; ay1[k]=v.y; ax2[k]=v.z; ay2[k]=v.w;
            qa[k] = q * ((v.z - v.x) * (v.w - v.y));
        }

        int wv = tid >> 6, ln = tid & 63;
        double acc = 0.0;
        #pragma unroll
        for (int s = 0; s < 2; ++s) {
            int b    = s ? b1 : b0;
            int no   = s ? no1 : no0;
            int no4  = (no + 3) & ~3;
            int base = s * NMAX;
            int cnt[APT];
            #pragma unroll
            for (int k = 0; k < APT; ++k) cnt[k] = 0;

            for (int n = 0; n < no4; n += 4) {
                #pragma unroll
                for (int u = 0; u < 4; ++u) {
                    float4 g  = sbox[base + n + u];
                    float  qg = sqg[base + n + u];
                    #pragma unroll
                    for (int k = 0; k < APT; ++k) {
                        float lx = fmaxf(ax1[k], g.x);
                        float ly = fmaxf(ay1[k], g.y);
                        float rx = fminf(ax2[k], g.z);
                        float ry = fminf(ay2[k], g.w);
                        float w  = fmaxf(rx - lx, 0.f);
                        float h  = fmaxf(ry - ly, 0.f);
                        float inter = w * h;
                        cnt[k] += (inter > qa[k] + qg) ? 1 : 0;
                    }
                }
            }
            const float2* cp = reinterpret_cast<const float2*>(classes) + (size_t)b * NANCH;
            #pragma unroll
            for (int k = 0; k < APT; ++k) {
                float2 c = cp[abase + k*THREADS];
                float p  = (cnt[k] > 0) ? c.y : c.x;
                float om = 1.0f - p;
                float f  = -om * om * __logf(p);
                acc += (double)(f * (1.0f + 10.0f * (float)cnt[k]));
            }
        }
        #pragma unroll
        for (int off = 32; off; off >>= 1) acc += __shfl_xor(acc, off, 64);
        if (ln == 0) sw[wv] = acc;
        __syncthreads();
        if (tid == 0) partials[bid] = sw[0] + sw[1] + sw[2] + sw[3];

    } else {
        // ==================== argmax role ====================
        int r    = bid - NB_CNT;
        int bu   = r >> 7;               // /BPB_A
        int blkc = r & (BPB_A - 1);
        if (bu >= *nbund) return;
        int wv = tid >> 6, ln = tid & 63;
        int abase = (blkc*4 + wv) * AC_ANCH;

        int lp = lanepk[bu*NMAX + ln];
        bool valid = lp >= 0;
        int gidx = valid ? ((lp >> 8)*NMAX + (lp & 255)) : 0;
        float4 gg = reinterpret_cast<const float4*>(gt)[gidx];
        float gx2 = gg.x + gg.z, gy2 = gg.y + gg.w;
        float gar = (gx2 - gg.x) * (gy2 - gg.y);

        // 4 independent chains (unroll slots); sa-form cross-mult:
        // iouA > iouB  <=>  interA*saB > interB*saA   (sa = areaA+areaB > 0)
        float bn[4] = {-1.f,-1.f,-1.f,-1.f};
        float bs[4] = { 1.f, 1.f, 1.f, 1.f};
        int   bj[4] = {0,0,0,0};
        const float4* ap = reinterpret_cast<const float4*>(anchors) + abase;
        for (int j = 0; j < AC_ANCH; j += 4) {
            #pragma unroll
            for (int u = 0; u < 4; ++u) {
                float4 v = ap[j + u];    // wave-uniform address -> broadcast
                float aar = (v.z - v.x) * (v.w - v.y);
                float lx = fmaxf(v.x, gg.x);
                float ly = fmaxf(v.y, gg.y);
                float rx = fminf(v.z, gx2);
                float ry = fminf(v.w, gy2);
                float w  = fmaxf(rx - lx, 0.f);
                float h  = fmaxf(ry - ly, 0.f);
                float inter = w * h;
                float sa    = aar + gar;            // > 0
                bool better = inter * bs[u] > bn[u] * sa;
                bn[u] = better ? inter : bn[u];
                bs[u] = better ? sa    : bs[u];
                bj[u] = better ? (j+u) : bj[u];
            }
        }
        if (valid) {
            ull best = 0;
            #pragma unroll
            for (int u = 0; u < 4; ++u) {
                float rr = bn[u] * __builtin_amdgcn_rcpf(bs[u]);  // order only
                unsigned aidx = (unsigned)(abase + bj[u]);
                ull pk = ((ull)__float_as_uint(rr) << 32)
                       | (ull)(0x7FFFFFFFu - aidx);
                best = pk > best ? pk : best;
            }
            atomicMax(&cells[(lp >> 8)*NMAX + (lp & 255)], best);
        }
    }
}

// One block, 1024 threads: sparse forced-positive correction (batch = tid>>6)
// + final reduction. Predicate expressions textually identical to the count
// role so the "old" contribution cancels exactly.
__global__ __launch_bounds__(1024) void k_tail(
    const float* __restrict__ thr_p,
    const float* __restrict__ classes,
    const float* __restrict__ anchors,
    const float* __restrict__ gt,
    const int*   __restrict__ nobj,
    const ull*   __restrict__ cells,
    const double* __restrict__ partials,
    float* __restrict__ out)
{
    int tid = threadIdx.x;
    int b = tid >> 6, n = tid & 63;
    float thr = *thr_p;
    float q   = thr / (1.0f + thr);

    __shared__ float4 sbox[NBATCH*NMAX];
    __shared__ float  sqg[NBATCH*NMAX];
    __shared__ int    sidx[NBATCH*NMAX];
    __shared__ double sdelta[NBATCH];
    __shared__ double sw[16];

    int n_obj = nobj[b];
    {
        float4 g = reinterpret_cast<const float4*>(gt)[b*NMAX + n];
        float x2 = g.x + g.z, y2 = g.y + g.w;
        sbox[tid] = make_float4(g.x, g.y, x2, y2);
        float gar = (x2 - g.x) * (y2 - g.y);
        sqg[tid]  = q * gar;
    }
    __syncthreads();

    int bi = -1; bool need = false;
    float4 av = make_float4(0.f,0.f,0.f,0.f);
    float qa = 0.f;
    if (n < n_obj) {
        ull pkv = cells[tid];
        bi = (int)(0x7FFFFFFFu - (unsigned)(pkv & 0xFFFFFFFFull));
        av = reinterpret_cast<const float4*>(anchors)[bi];
        float aar = (av.z - av.x) * (av.w - av.y);
        qa = q * aar;
        float4 g = sbox[tid];
        float lx = fmaxf(av.x, g.x), ly = fmaxf(av.y, g.y);
        float rx = fminf(av.z, g.z), ry = fminf(av.w, g.w);
        float w  = fmaxf(rx - lx, 0.f), h = fmaxf(ry - ly, 0.f);
        float inter = w * h;
        need = !(inter > qa + sqg[tid]);  // forced adds a bit only if !pos
    }
    sidx[tid] = need ? bi : -1;
    __syncthreads();

    double delta = 0.0;
    if (need) {
        bool first = true; int extra = 0;
        int base = b * NMAX;
        for (int m = 0; m < NMAX; ++m) {
            if (sidx[base + m] == bi) { if (m < n) first = false; ++extra; }
        }
        if (first) {
            int count = 0;
            for (int m = 0; m < n_obj; ++m) {
                float4 g = sbox[base + m];
                float lx = fmaxf(av.x, g.x), ly = fmaxf(av.y, g.y);
                float rx = fminf(av.z, g.z), ry = fminf(av.w, g.w);
                float w  = fmaxf(rx - lx, 0.f), h = fmaxf(ry - ly, 0.f);
                float inter = w * h;
                count += (inter > qa + sqg[base + m]) ? 1 : 0;
            }
            float2 c = reinterpret_cast<const float2*>(classes)[(size_t)b * NANCH + bi];
            float po = (count > 0) ? c.y : c.x;
            float oo = 1.0f - po;
            float fo = -oo * oo * __logf(po);
            float oldc = fo * (1.0f + 10.0f * (float)count);
            int cn = count + extra;
            float pn = (cn > 0) ? c.y : c.x;
            float on = 1.0f - pn;
            float fn = -on * on * __logf(pn);
            float newc = fn * (1.0f + 10.0f * (float)cn);
            delta = (double)newc - (double)oldc;
        }
    }
    #pragma unroll
    for (int off = 32; off; off >>= 1) delta += __shfl_xor(delta, off, 64);
    if (n == 0) sdelta[b] = delta;
    __syncthreads();

    // final: 1024 count partials map 1:1 to threads, plus 16 deltas
    double v = partials[tid];
    if (tid < NBATCH) v += sdelta[tid];
    #pragma unroll
    for (int off = 32; off; off >>= 1) v += __shfl_xor(v, off, 64);
    if ((tid & 63) == 0) sw[tid >> 6] = v;
    __syncthreads();
    if (tid == 0) {
        double tot = 0.0;
        #pragma unroll
        for (int i = 0; i < 16; ++i) tot += sw[i];
        double cls = tot * (0.01 / 16.0);
        out[0] = (float)cls;   // total = class + coord(0)
        out[1] = (float)cls;
        out[2] = 0.0f;
    }
}

extern "C" void kernel_launch(void* const* d_in, const int* in_sizes, int n_in,
                              void* d_out, int out_size, void* d_ws, size_t ws_size,
                              hipStream_t stream) {
    const float* thr     = (const float*)d_in[0];
    const float* classes = (const float*)d_in[1];
    const float* anchors = (const float*)d_in[2];
    const float* gt      = (const float*)d_in[3];
    const int*   nobj    = (const int*)d_in[4];
    float* out = (float*)d_out;

    char* ws = (char*)d_ws;
    ull*    cells    = (ull*)(ws + 0);
    int*    pairs    = (int*)(ws + 8192);
    int*    lanepk   = (int*)(ws + 8256);
    int*    nbund    = (int*)(ws + 12352);
    double* partials = (double*)(ws + 12416);

    k_setup<<<1, 64, 0, stream>>>(nobj, cells, pairs, lanepk, nbund);
    k_main<<<GRID_MAIN, THREADS, 0, stream>>>(thr, classes, anchors, gt, nobj,
                                              pairs, lanepk, nbund, cells, partials);
    k_tail<<<1, 1024, 0, stream>>>(thr, classes, anchors, gt, nobj, cells, partials, out);
}

// Round 10
// 99.536 us; speedup vs baseline: 3.0737x; 1.0744x over previous
//
#include <hip/hip_runtime.h>

typedef unsigned long long ull;

#define NANCH    131072
#define NMAX     64
#define NBATCH   16
#define THREADS  256
#define APT      4                       // count role: anchors per thread
#define ACH      (THREADS*APT)           // 1024 anchors per count block
#define NPAIR    8
#define NB_CNT   ((NANCH/ACH)*NPAIR)     // 1024 count blocks
#define AC_ANCH  256                     // argmax role: anchors per wave-chunk
#define BPB_A    128                     // blocks per bundle (4 waves each)
#define MAXB     16
#define NB_ARG   (MAXB*BPB_A)            // 2048 argmax blocks
#define GRID_MAIN (NB_CNT+NB_ARG)        // 3072 = 1024*3 (1:2 interleave)

// ---------------------------------------------------------------------------
// ws layout (bytes):
//   0      : ull cells[1024]       per-(batch,gt) packed argmax
//   8192   : int pairs[16]
//   8256   : int lanepk[16*64]
//   12352  : int nbund
//   12416  : double partials[1024]
//   24576  : float parea[NANCH]    (only if ws_size >= WS_NEED)
// cells packed as (r_bits<<32)|(0x7FFFFFFF-idx), r = inter/(areaA+areaB) --
// monotone bijection of iou, >= 0, so float bits are unsigned-monotonic;
// ties -> larger low word -> smaller anchor index == JAX argmax
// first-occurrence semantics.
// ---------------------------------------------------------------------------
#define WS_PAREA_OFF 24576
#define WS_NEED (WS_PAREA_OFF + NANCH*4)

template<bool BIG>
__global__ __launch_bounds__(256) void k_setup(
    const int* __restrict__ nobj, const float* __restrict__ anchors,
    ull* __restrict__ cells, int* __restrict__ pairs,
    int* __restrict__ lanepk, int* __restrict__ nbund,
    float* __restrict__ parea)
{
    int tid = threadIdx.x;
    if (BIG) {
        for (int i = blockIdx.x*256 + tid; i < NANCH; i += gridDim.x*256) {
            float4 v = reinterpret_cast<const float4*>(anchors)[i];
            parea[i] = (v.z - v.x) * (v.w - v.y);
        }
    }
    if (blockIdx.x != 0) return;
    for (int i = tid; i < NBATCH*NMAX; i += 256) cells[i] = 0ull;
    for (int i = tid; i < MAXB*NMAX; i += 256) lanepk[i] = -1;
    __syncthreads();
    if (tid) return;
    // sort batches desc by n_obj (stable)
    int ord[NBATCH], key[NBATCH];
    for (int i = 0; i < NBATCH; ++i) { ord[i] = i; key[i] = nobj[i]; }
    for (int i = 1; i < NBATCH; ++i) {
        int k = key[i], o = ord[i], j = i-1;
        while (j >= 0 && key[j] < k) { key[j+1]=key[j]; ord[j+1]=ord[j]; --j; }
        key[j+1] = k; ord[j+1] = o;
    }
    // count-role pairing: big + small -> near-equal sums
    for (int p = 0; p < NPAIR; ++p) {
        pairs[2*p]   = ord[p];
        pairs[2*p+1] = ord[NBATCH-1-p];
    }
    // argmax-role: first-fit-decreasing into 64-lane bundles
    int rem[MAXB];
    int nb = 0;
    for (int i = 0; i < NBATCH; ++i) {
        int n = key[i], f = -1;
        for (int x = 0; x < nb; ++x) if (rem[x] >= n) { f = x; break; }
        if (f < 0) { f = nb++; rem[f] = NMAX; }
        int st = NMAX - rem[f];
        for (int k = 0; k < n; ++k) lanepk[f*NMAX + st + k] = (ord[i] << 8) | k;
        rem[f] -= n;
    }
    *nbund = nb;
}

// Two roles, 1:2 interleaved in dispatch order so the resident mix stays
// proportional and the drain tail is heterogeneous.
//  - count role: anchor-per-lane, gts from LDS, 12-op inner, NO reductions.
//  - argmax role: (batch,gt)-per-lane via bundles, 8 independent unroll-slot
//    chains (8+2 uniform loads in flight), one atomicMax per lane at the end.
template<bool BIG>
__global__ __launch_bounds__(THREADS) void k_main(
    const float* __restrict__ thr_p,
    const float* __restrict__ classes,   // [B,A,2]
    const float* __restrict__ anchors,   // [A,4] xyxy
    const float* __restrict__ gt,        // [B,NMAX,4] xywh
    const int*   __restrict__ nobj,
    const int*   __restrict__ pairs,
    const int*   __restrict__ lanepk,
    const int*   __restrict__ nbund,
    const float* __restrict__ parea,
    ull* __restrict__ cells,
    double* __restrict__ partials)
{
    int bid0 = blockIdx.x;
    int tid  = threadIdx.x;
    float thr = *thr_p;
    float q   = thr / (1.0f + thr);      // iou>thr <=> inter > q*aarea + q*garea
    bool is_cnt = (bid0 % 3) == 0;
    int  bid    = is_cnt ? (bid0 / 3) : ((bid0 / 3) * 2 + (bid0 % 3) - 1);

    if (is_cnt) {
        // ==================== count + focal role ====================
        int chunk = bid >> 3, pr = bid & 7;
        int b0 = pairs[2*pr], b1 = pairs[2*pr+1];
        int no0 = nobj[b0], no1 = nobj[b1];

        __shared__ float4 sbox[2*NMAX];  // xyxy (degenerate-padded)
        __shared__ float  sqg[2*NMAX];   // q*garea (+inf for pads)
        __shared__ double sw[4];
        if (tid < 2*NMAX) {
            int s = tid >> 6, n = tid & 63;
            int b  = s ? b1 : b0;
            int no = s ? no1 : no0;
            float4 g = reinterpret_cast<const float4*>(gt)[b*NMAX + n];
            float x2 = g.x + g.z, y2 = g.y + g.w;
            float4 box = make_float4(g.x, g.y, x2, y2);
            float  qg  = q * ((x2 - g.x) * (y2 - g.y));
            if (n >= no) { box = make_float4(4.f,4.f,4.f,4.f); qg = __builtin_inff(); }
            sbox[tid] = box; sqg[tid] = qg;
        }
        __syncthreads();

        float ax1[APT], ay1[APT], ax2[APT], ay2[APT], qa[APT];
        int abase = chunk * ACH + tid;
        #pragma unroll
        for (int k = 0; k < APT; ++k) {
            float4 v = reinterpret_cast<const float4*>(anchors)[abase + k*THREADS];
            ax1[k]=v.x; ay1[k]=v.y; ax2[k]=v.z; ay2[k]=v.w;
            qa[k] = q * ((v.z - v.x) * (v.w - v.y));
        }

        int wv = tid >> 6, ln = tid & 63;
        double acc = 0.0;
        #pragma unroll
        for (int s = 0; s < 2; ++s) {
            int b    = s ? b1 : b0;
            int no   = s ? no1 : no0;
            int no4  = (no + 3) & ~3;
            int base = s * NMAX;
            int cnt[APT];
            #pragma unroll
            for (int k = 0; k < APT; ++k) cnt[k] = 0;

            for (int n = 0; n < no4; n += 4) {
                #pragma unroll
                for (int u = 0; u < 4; ++u) {
                    float4 g  = sbox[base + n + u];
                    float  qg = sqg[base + n + u];
                    #pragma unroll
                    for (int k = 0; k < APT; ++k) {
                        float lx = fmaxf(ax1[k], g.x);
                        float ly = fmaxf(ay1[k], g.y);
                        float rx = fminf(ax2[k], g.z);
                        float ry = fminf(ay2[k], g.w);
                        float w  = fmaxf(rx - lx, 0.f);
                        float h  = fmaxf(ry - ly, 0.f);
                        float inter = w * h;
                        cnt[k] += (inter > qa[k] + qg) ? 1 : 0;
                    }
                }
            }
            const float2* cp = reinterpret_cast<const float2*>(classes) + (size_t)b * NANCH;
            #pragma unroll
            for (int k = 0; k < APT; ++k) {
                float2 c = cp[abase + k*THREADS];
                float p  = (cnt[k] > 0) ? c.y : c.x;
                float om = 1.0f - p;
                float f  = -om * om * __logf(p);
                acc += (double)(f * (1.0f + 10.0f * (float)cnt[k]));
            }
        }
        #pragma unroll
        for (int off = 32; off; off >>= 1) acc += __shfl_xor(acc, off, 64);
        if (ln == 0) sw[wv] = acc;
        __syncthreads();
        if (tid == 0) partials[bid] = sw[0] + sw[1] + sw[2] + sw[3];

    } else {
        // ==================== argmax role ====================
        int bu   = bid >> 7;             // /BPB_A
        int blkc = bid & (BPB_A - 1);
        if (bu >= *nbund) return;
        int wv = tid >> 6, ln = tid & 63;
        int abase = (blkc*4 + wv) * AC_ANCH;

        int lp = lanepk[bu*NMAX + ln];
        bool valid = lp >= 0;
        int gidx = valid ? ((lp >> 8)*NMAX + (lp & 255)) : 0;
        float4 gg = reinterpret_cast<const float4*>(gt)[gidx];
        float gx2 = gg.x + gg.z, gy2 = gg.y + gg.w;
        float gar = (gx2 - gg.x) * (gy2 - gg.y);

        // 8 independent chains; sa-form cross-mult:
        // iouA > iouB  <=>  interA*saB > interB*saA   (sa = areaA+areaB > 0)
        float bn[8], bs[8]; int bj[8];
        #pragma unroll
        for (int u = 0; u < 8; ++u) { bn[u] = -1.f; bs[u] = 1.f; bj[u] = 0; }
        const float4* ap  = reinterpret_cast<const float4*>(anchors) + abase;
        const float4* pa4 = reinterpret_cast<const float4*>(parea + abase);
        for (int j = 0; j < AC_ANCH; j += 8) {
            float4 v[8]; float ar[8];
            #pragma unroll
            for (int u = 0; u < 8; ++u) v[u] = ap[j + u];   // uniform -> broadcast
            if (BIG) {
                float4 a0 = pa4[(j >> 2)], a1 = pa4[(j >> 2) + 1];
                ar[0]=a0.x; ar[1]=a0.y; ar[2]=a0.z; ar[3]=a0.w;
                ar[4]=a1.x; ar[5]=a1.y; ar[6]=a1.z; ar[7]=a1.w;
            } else {
                #pragma unroll
                for (int u = 0; u < 8; ++u)
                    ar[u] = (v[u].z - v[u].x) * (v[u].w - v[u].y);
            }
            #pragma unroll
            for (int u = 0; u < 8; ++u) {
                float lx = fmaxf(v[u].x, gg.x);
                float ly = fmaxf(v[u].y, gg.y);
                float rx = fminf(v[u].z, gx2);
                float ry = fminf(v[u].w, gy2);
                float w  = fmaxf(rx - lx, 0.f);
                float h  = fmaxf(ry - ly, 0.f);
                float inter = w * h;
                float sa    = ar[u] + gar;          // > 0
                bool better = inter * bs[u] > bn[u] * sa;
                bn[u] = better ? inter : bn[u];
                bs[u] = better ? sa    : bs[u];
                bj[u] = better ? (j+u) : bj[u];
            }
        }
        if (valid) {
            ull best = 0;
            #pragma unroll
            for (int u = 0; u < 8; ++u) {
                float rr = bn[u] * __builtin_amdgcn_rcpf(bs[u]);  // order only
                unsigned aidx = (unsigned)(abase + bj[u]);
                ull pk = ((ull)__float_as_uint(rr) << 32)
                       | (ull)(0x7FFFFFFFu - aidx);
                best = pk > best ? pk : best;
            }
            atomicMax(&cells[(lp >> 8)*NMAX + (lp & 255)], best);
        }
    }
}

// One block, 1024 threads: sparse forced-positive correction (batch = tid>>6)
// + final reduction. Predicate expressions textually identical to the count
// role so the "old" contribution cancels exactly.
__global__ __launch_bounds__(1024) void k_tail(
    const float* __restrict__ thr_p,
    const float* __restrict__ classes,
    const float* __restrict__ anchors,
    const float* __restrict__ gt,
    const int*   __restrict__ nobj,
    const ull*   __restrict__ cells,
    const double* __restrict__ partials,
    float* __restrict__ out)
{
    int tid = threadIdx.x;
    int b = tid >> 6, n = tid & 63;
    float thr = *thr_p;
    float q   = thr / (1.0f + thr);

    __shared__ float4 sbox[NBATCH*NMAX];
    __shared__ float  sqg[NBATCH*NMAX];
    __shared__ int    sidx[NBATCH*NMAX];
    __shared__ double sdelta[NBATCH];
    __shared__ double sw[16];

    int n_obj = nobj[b];
    {
        float4 g = reinterpret_cast<const float4*>(gt)[b*NMAX + n];
        float x2 = g.x + g.z, y2 = g.y + g.w;
        sbox[tid] = make_float4(g.x, g.y, x2, y2);
        float gar = (x2 - g.x) * (y2 - g.y);
        sqg[tid]  = q * gar;
    }
    __syncthreads();

    int bi = -1; bool need = false;
    float4 av = make_float4(0.f,0.f,0.f,0.f);
    float qa = 0.f;
    if (n < n_obj) {
        ull pkv = cells[tid];
        bi = (int)(0x7FFFFFFFu - (unsigned)(pkv & 0xFFFFFFFFull));
        av = reinterpret_cast<const float4*>(anchors)[bi];
        float aar = (av.z - av.x) * (av.w - av.y);
        qa = q * aar;
        float4 g = sbox[tid];
        float lx = fmaxf(av.x, g.x), ly = fmaxf(av.y, g.y);
        float rx = fminf(av.z, g.z), ry = fminf(av.w, g.w);
        float w  = fmaxf(rx - lx, 0.f), h = fmaxf(ry - ly, 0.f);
        float inter = w * h;
        need = !(inter > qa + sqg[tid]);  // forced adds a bit only if !pos
    }
    sidx[tid] = need ? bi : -1;
    __syncthreads();

    double delta = 0.0;
    if (need) {
        bool first = true; int extra = 0;
        int base = b * NMAX;
        for (int m = 0; m < NMAX; ++m) {
            if (sidx[base + m] == bi) { if (m < n) first = false; ++extra; }
        }
        if (first) {
            int count = 0;
            for (int m = 0; m < n_obj; ++m) {
                float4 g = sbox[base + m];
                float lx = fmaxf(av.x, g.x), ly = fmaxf(av.y, g.y);
                float rx = fminf(av.z, g.z), ry = fminf(av.w, g.w);
                float w  = fmaxf(rx - lx, 0.f), h = fmaxf(ry - ly, 0.f);
                float inter = w * h;
                count += (inter > qa + sqg[base + m]) ? 1 : 0;
            }
            float2 c = reinterpret_cast<const float2*>(classes)[(size_t)b * NANCH + bi];
            float po = (count > 0) ? c.y : c.x;
            float oo = 1.0f - po;
            float fo = -oo * oo * __logf(po);
            float oldc = fo * (1.0f + 10.0f * (float)count);
            int cn = count + extra;
            float pn = (cn > 0) ? c.y : c.x;
            float on = 1.0f - pn;
            float fn = -on * on * __logf(pn);
            float newc = fn * (1.0f + 10.0f * (float)cn);
            delta = (double)newc - (double)oldc;
        }
    }
    #pragma unroll
    for (int off = 32; off; off >>= 1) delta += __shfl_xor(delta, off, 64);
    if (n == 0) sdelta[b] = delta;
    __syncthreads();

    // final: 1024 count partials map 1:1 to threads, plus 16 deltas
    double v = partials[tid];
    if (tid < NBATCH) v += sdelta[tid];
    #pragma unroll
    for (int off = 32; off; off >>= 1) v += __shfl_xor(v, off, 64);
    if ((tid & 63) == 0) sw[tid >> 6] = v;
    __syncthreads();
    if (tid == 0) {
        double tot = 0.0;
        #pragma unroll
        for (int i = 0; i < 16; ++i) tot += sw[i];
        double cls = tot * (0.01 / 16.0);
        out[0] = (float)cls;   // total = class + coord(0)
        out[1] = (float)cls;
        out[2] = 0.0f;
    }
}

extern "C" void kernel_launch(void* const* d_in, const int* in_sizes, int n_in,
                              void* d_out, int out_size, void* d_ws, size_t ws_size,
                              hipStream_t stream) {
    const float* thr     = (const float*)d_in[0];
    const float* classes = (const float*)d_in[1];
    const float* anchors = (const float*)d_in[2];
    const float* gt      = (const float*)d_in[3];
    const int*   nobj    = (const int*)d_in[4];
    float* out = (float*)d_out;

    char* ws = (char*)d_ws;
    ull*    cells    = (ull*)(ws + 0);
    int*    pairs    = (int*)(ws + 8192);
    int*    lanepk   = (int*)(ws + 8256);
    int*    nbund    = (int*)(ws + 12352);
    double* partials = (double*)(ws + 12416);
    float*  parea    = (float*)(ws + WS_PAREA_OFF);

    bool big = ws_size >= (size_t)WS_NEED;
    if (big) {
        k_setup<true><<<128, 256, 0, stream>>>(nobj, anchors, cells, pairs,
                                               lanepk, nbund, parea);
        k_main<true><<<GRID_MAIN, THREADS, 0, stream>>>(thr, classes, anchors, gt,
                nobj, pairs, lanepk, nbund, parea, cells, partials);
    } else {
        k_setup<false><<<1, 256, 0, stream>>>(nobj, anchors, cells, pairs,
                                              lanepk, nbund, parea);
        k_main<false><<<GRID_MAIN, THREADS, 0, stream>>>(thr, classes, anchors, gt,
                nobj, pairs, lanepk, nbund, parea, cells, partials);
    }
    k_tail<<<1, 1024, 0, stream>>>(thr, classes, anchors, gt, nobj, cells, partials, out);
}